// Round 1
// baseline (1401.001 us; speedup 1.0000x reference)
//
#include <hip/hip_runtime.h>
#include <math.h>

#define S 4096
#define CNUM 128
#define BATCH 4
#define SCALE 0.25f
#define EPSLN 1e-5f

__device__ __forceinline__ float gelu_exact(float x) {
    return 0.5f * x * (1.0f + erff(x * 0.7071067811865476f));
}

// ---------------- Kernel A: transpose [B,C,S] -> [B,S,C] + LayerNorm1 ----------------
__global__ __launch_bounds__(256) void ln1_transpose(
    const float* __restrict__ x, const float* __restrict__ w, const float* __restrict__ bb,
    float* __restrict__ xl, float* __restrict__ t)
{
    __shared__ float tile[128][65];
    __shared__ float mu[64], rs[64];
    const int b = blockIdx.y;
    const int s0 = blockIdx.x * 64;
    const float* xb = x + (size_t)b * CNUM * S;
    for (int i = threadIdx.x; i < 128 * 64; i += 256) {
        int c = i >> 6, sl = i & 63;
        tile[c][sl] = xb[(size_t)c * S + s0 + sl];
    }
    __syncthreads();
    if (threadIdx.x < 64) {
        float sum = 0.f, sq = 0.f;
        for (int c = 0; c < 128; ++c) {
            float v = tile[c][threadIdx.x];
            sum += v; sq += v * v;
        }
        float m = sum * (1.f / 128.f);
        float var = sq * (1.f / 128.f) - m * m;
        mu[threadIdx.x] = m;
        rs[threadIdx.x] = rsqrtf(var + EPSLN);
    }
    __syncthreads();
    for (int i = threadIdx.x; i < 128 * 64; i += 256) {
        int c = i & 127, sl = i >> 7;
        float v = tile[c][sl];
        size_t idx = ((size_t)b * S + s0 + sl) * CNUM + c;
        t[idx] = v;
        xl[idx] = (v - mu[sl]) * rs[sl] * w[c] + bb[c];
    }
}

// ---------------- Generic fp32 GEMM: C = A[M,K] @ B[K,N] + bias, epilogues ----------------
// epi: 0 = bias; 1 = bias+gelu; 2 = bias+residual; 3 = gelu(bias-added)+residual
__global__ __launch_bounds__(256) void gemm64(
    const float* __restrict__ A, const float* __restrict__ Bw,
    const float* __restrict__ bias, const float* __restrict__ res,
    float* __restrict__ C, int M, int N, int K, int epi)
{
    __shared__ float As[16][65];
    __shared__ float Bs[16][65];
    const int bm = blockIdx.y * 64;
    const int bn = blockIdx.x * 64;
    const int tid = threadIdx.x;
    const int tx = tid & 15, ty = tid >> 4;
    float acc[4][4] = {};
    for (int k0 = 0; k0 < K; k0 += 16) {
        #pragma unroll
        for (int i = 0; i < 4; ++i) {
            int idx = tid + i * 256;
            int r = idx >> 4, c = idx & 15;
            As[c][r] = A[(size_t)(bm + r) * K + k0 + c];
        }
        #pragma unroll
        for (int i = 0; i < 4; ++i) {
            int idx = tid + i * 256;
            int r = idx >> 6, c = idx & 63;
            Bs[r][c] = Bw[(size_t)(k0 + r) * N + bn + c];
        }
        __syncthreads();
        #pragma unroll
        for (int kk = 0; kk < 16; ++kk) {
            float a[4], bvec[4];
            #pragma unroll
            for (int i = 0; i < 4; ++i) a[i] = As[kk][ty * 4 + i];
            #pragma unroll
            for (int j = 0; j < 4; ++j) bvec[j] = Bs[kk][tx * 4 + j];
            #pragma unroll
            for (int i = 0; i < 4; ++i)
                #pragma unroll
                for (int j = 0; j < 4; ++j)
                    acc[i][j] += a[i] * bvec[j];
        }
        __syncthreads();
    }
    #pragma unroll
    for (int i = 0; i < 4; ++i) {
        int row = bm + ty * 4 + i;
        #pragma unroll
        for (int j = 0; j < 4; ++j) {
            int col = bn + tx * 4 + j;
            float v = acc[i][j] + bias[col];
            if (epi == 1) v = gelu_exact(v);
            else if (epi == 2) v += res[(size_t)row * N + col];
            else if (epi == 3) v = gelu_exact(v) + res[(size_t)row * N + col];
            C[(size_t)row * N + col] = v;
        }
    }
}

// ---------------- Scores: Sc[q,k] = SCALE * sum_c Q[q,c]*K[k,c]  (NT GEMM) ----------------
__global__ __launch_bounds__(256) void scores_nt(
    const float* __restrict__ Q, const float* __restrict__ Km, float* __restrict__ Sc)
{
    __shared__ float As[16][65];
    __shared__ float Bs[16][65];
    const int bm = blockIdx.y * 64;
    const int bn = blockIdx.x * 64;
    const int tid = threadIdx.x;
    const int tx = tid & 15, ty = tid >> 4;
    float acc[4][4] = {};
    for (int k0 = 0; k0 < CNUM; k0 += 16) {
        #pragma unroll
        for (int i = 0; i < 4; ++i) {
            int idx = tid + i * 256;
            int r = idx >> 4, c = idx & 15;
            As[c][r] = Q[(size_t)(bm + r) * CNUM + k0 + c];
            Bs[c][r] = Km[(size_t)(bn + r) * CNUM + k0 + c];
        }
        __syncthreads();
        #pragma unroll
        for (int kk = 0; kk < 16; ++kk) {
            float a[4], bvec[4];
            #pragma unroll
            for (int i = 0; i < 4; ++i) a[i] = As[kk][ty * 4 + i];
            #pragma unroll
            for (int j = 0; j < 4; ++j) bvec[j] = Bs[kk][tx * 4 + j];
            #pragma unroll
            for (int i = 0; i < 4; ++i)
                #pragma unroll
                for (int j = 0; j < 4; ++j)
                    acc[i][j] += a[i] * bvec[j];
        }
        __syncthreads();
    }
    #pragma unroll
    for (int i = 0; i < 4; ++i)
        #pragma unroll
        for (int j = 0; j < 4; ++j)
            Sc[(size_t)(bm + ty * 4 + i) * S + bn + tx * 4 + j] = acc[i][j] * SCALE;
}

// ---------------- Column-softmax stats over the QUERY axis (rows of Sc) ----------------
__global__ __launch_bounds__(256) void colstat1(
    const float* __restrict__ Sc, float* __restrict__ pm, float* __restrict__ pl)
{
    int col = blockIdx.x * 256 + threadIdx.x;
    int r0 = blockIdx.y * 256;
    float m = -INFINITY, l = 0.f;
    for (int r = r0; r < r0 + 256; ++r) {
        float v = Sc[(size_t)r * S + col];
        if (v > m) { l = l * __expf(m - v) + 1.f; m = v; }
        else l += __expf(v - m);
    }
    pm[(size_t)blockIdx.y * S + col] = m;
    pl[(size_t)blockIdx.y * S + col] = l;
}

__global__ __launch_bounds__(256) void colstat2(
    const float* __restrict__ pm, const float* __restrict__ pl,
    float* __restrict__ mcol, float* __restrict__ rl)
{
    int col = blockIdx.x * 256 + threadIdx.x;
    float M = -INFINITY;
    for (int i = 0; i < 16; ++i) M = fmaxf(M, pm[(size_t)i * S + col]);
    float L = 0.f;
    for (int i = 0; i < 16; ++i) L += pl[(size_t)i * S + col] * __expf(pm[(size_t)i * S + col] - M);
    mcol[col] = M;
    rl[col] = 1.0f / L;
}

// ---------------- attn@V with exp applied on the fly; split-K=4 + atomicAdd ----------------
__global__ __launch_bounds__(256) void attnv(
    const float* __restrict__ Sc, const float* __restrict__ mcol,
    const float* __restrict__ rl, const float* __restrict__ V, float* __restrict__ O)
{
    __shared__ float As[16][65];
    __shared__ float Bs[16][65];
    const int bm = blockIdx.y * 64;
    const int bn = blockIdx.x * 64;
    const int kstart = blockIdx.z * (S / 4);
    const int tid = threadIdx.x;
    const int tx = tid & 15, ty = tid >> 4;
    float acc[4][4] = {};
    for (int k0 = kstart; k0 < kstart + S / 4; k0 += 16) {
        #pragma unroll
        for (int i = 0; i < 4; ++i) {
            int idx = tid + i * 256;
            int r = idx >> 4, c = idx & 15;
            int kk = k0 + c;
            As[c][r] = __expf(Sc[(size_t)(bm + r) * S + kk] - mcol[kk]) * rl[kk];
        }
        #pragma unroll
        for (int i = 0; i < 4; ++i) {
            int idx = tid + i * 256;
            int r = idx >> 6, c = idx & 63;
            Bs[r][c] = V[(size_t)(k0 + r) * CNUM + bn + c];
        }
        __syncthreads();
        #pragma unroll
        for (int kk = 0; kk < 16; ++kk) {
            float a[4], bvec[4];
            #pragma unroll
            for (int i = 0; i < 4; ++i) a[i] = As[kk][ty * 4 + i];
            #pragma unroll
            for (int j = 0; j < 4; ++j) bvec[j] = Bs[kk][tx * 4 + j];
            #pragma unroll
            for (int i = 0; i < 4; ++i)
                #pragma unroll
                for (int j = 0; j < 4; ++j)
                    acc[i][j] += a[i] * bvec[j];
        }
        __syncthreads();
    }
    #pragma unroll
    for (int i = 0; i < 4; ++i)
        #pragma unroll
        for (int j = 0; j < 4; ++j)
            atomicAdd(&O[(size_t)(bm + ty * 4 + i) * CNUM + bn + tx * 4 + j], acc[i][j]);
}

// ---------------- LayerNorm over rows of [M,128]: one wave per row ----------------
__global__ __launch_bounds__(256) void ln_rows(
    const float* __restrict__ y, const float* __restrict__ w, const float* __restrict__ bb,
    float* __restrict__ z)
{
    int row = blockIdx.x * 4 + (threadIdx.x >> 6);
    int lane = threadIdx.x & 63;
    const float* yr = y + (size_t)row * CNUM;
    float v0 = yr[lane], v1 = yr[lane + 64];
    float sum = v0 + v1, sq = v0 * v0 + v1 * v1;
    #pragma unroll
    for (int off = 32; off; off >>= 1) {
        sum += __shfl_xor(sum, off);
        sq  += __shfl_xor(sq, off);
    }
    float mean = sum * (1.f / 128.f);
    float var = sq * (1.f / 128.f) - mean * mean;
    float r = rsqrtf(var + EPSLN);
    z[(size_t)row * CNUM + lane]      = (v0 - mean) * r * w[lane] + bb[lane];
    z[(size_t)row * CNUM + lane + 64] = (v1 - mean) * r * w[lane + 64] + bb[lane + 64];
}

// ---------------- Final transpose [B,S,C] -> [B,C,S] ----------------
__global__ void transpose_out(const float* __restrict__ tf, float* __restrict__ out)
{
    __shared__ float tile[32][33];
    const int b = blockIdx.z;
    const int s0 = blockIdx.x * 32, c0 = blockIdx.y * 32;
    for (int i = threadIdx.y; i < 32; i += 8)
        tile[i][threadIdx.x] = tf[((size_t)b * S + s0 + i) * CNUM + c0 + threadIdx.x];
    __syncthreads();
    for (int i = threadIdx.y; i < 32; i += 8)
        out[((size_t)b * CNUM + c0 + i) * S + s0 + threadIdx.x] = tile[threadIdx.x][i];
}

extern "C" void kernel_launch(void* const* d_in, const int* in_sizes, int n_in,
                              void* d_out, int out_size, void* d_ws, size_t ws_size,
                              hipStream_t stream)
{
    (void)in_sizes; (void)n_in; (void)out_size; (void)ws_size;
    const float* x    = (const float*)d_in[0];
    const float* ln1w = (const float*)d_in[1];
    const float* ln1b = (const float*)d_in[2];
    const float* wq   = (const float*)d_in[3];
    const float* bq   = (const float*)d_in[4];
    const float* wk   = (const float*)d_in[5];
    const float* bk   = (const float*)d_in[6];
    const float* wv   = (const float*)d_in[7];
    const float* bv   = (const float*)d_in[8];
    const float* wo   = (const float*)d_in[9];
    const float* bo   = (const float*)d_in[10];
    const float* ln2w = (const float*)d_in[11];
    const float* ln2b = (const float*)d_in[12];
    const float* w1   = (const float*)d_in[13];
    const float* b1   = (const float*)d_in[14];
    const float* w2   = (const float*)d_in[15];
    const float* b2   = (const float*)d_in[16];
    float* out = (float*)d_out;

    float* ws = (float*)d_ws;
    const size_t NSC = (size_t)BATCH * S * CNUM;   // 2,097,152 floats
    float* xl     = ws;                 // also reused as z (LN2 out)
    float* t      = xl + NSC;
    float* q      = t + NSC;
    float* k      = q + NSC;
    float* v      = k + NSC;
    float* attout = v + NSC;            // also reused as tf (final pre-transpose)
    float* y      = attout + NSC;
    float* Sc     = y + NSC;            // 16,777,216 floats; reused as MLP hidden h
    float* pm     = Sc + (size_t)S * S;
    float* pl     = pm + 16 * S;
    float* mcol   = pl + 16 * S;
    float* rlc    = mcol + S;

    const int M = BATCH * S;            // 16384

    ln1_transpose<<<dim3(S / 64, BATCH), 256, 0, stream>>>(x, ln1w, ln1b, xl, t);

    gemm64<<<dim3(2, M / 64), 256, 0, stream>>>(xl, wq, bq, nullptr, q, M, 128, 128, 0);
    gemm64<<<dim3(2, M / 64), 256, 0, stream>>>(xl, wk, bk, nullptr, k, M, 128, 128, 0);
    gemm64<<<dim3(2, M / 64), 256, 0, stream>>>(xl, wv, bv, nullptr, v, M, 128, 128, 0);

    hipMemsetAsync(attout, 0, NSC * sizeof(float), stream);

    for (int b = 0; b < BATCH; ++b) {
        const float* qb = q + (size_t)b * S * CNUM;
        const float* kb = k + (size_t)b * S * CNUM;
        const float* vb = v + (size_t)b * S * CNUM;
        float* ob = attout + (size_t)b * S * CNUM;
        scores_nt<<<dim3(S / 64, S / 64), 256, 0, stream>>>(qb, kb, Sc);
        colstat1<<<dim3(S / 256, 16), 256, 0, stream>>>(Sc, pm, pl);
        colstat2<<<dim3(S / 256), 256, 0, stream>>>(pm, pl, mcol, rlc);
        attnv<<<dim3(2, S / 64, 4), 256, 0, stream>>>(Sc, mcol, rlc, vb, ob);
    }

    // y = attout @ wo + bo + t
    gemm64<<<dim3(2, M / 64), 256, 0, stream>>>(attout, wo, bo, t, y, M, 128, 128, 2);
    // z = LN2(y)   (z aliases xl)
    ln_rows<<<M / 4, 256, 0, stream>>>(y, ln2w, ln2b, xl);
    // h = gelu(z @ w1 + b1)   (h aliases Sc)
    gemm64<<<dim3(4, M / 64), 256, 0, stream>>>(xl, w1, b1, nullptr, Sc, M, 256, 128, 1);
    // tf = gelu(h @ w2 + b2) + y   (tf aliases attout)
    gemm64<<<dim3(2, M / 64), 256, 0, stream>>>(Sc, w2, b2, y, attout, M, 128, 256, 3);
    // out = transpose(tf)
    transpose_out<<<dim3(S / 32, CNUM / 32, BATCH), dim3(32, 8), 0, stream>>>(attout, out);
}

// Round 2
// 787.747 us; speedup vs baseline: 1.7785x; 1.7785x over previous
//
#include <hip/hip_runtime.h>
#include <math.h>

#define S 4096
#define CNUM 128
#define BATCH 4
#define SCALE 0.25f
#define EPSLN 1e-5f

typedef __attribute__((ext_vector_type(8))) short bf16x8;
typedef __attribute__((ext_vector_type(4))) float f32x4;

__device__ __forceinline__ float gelu_exact(float x) {
    return 0.5f * x * (1.0f + erff(x * 0.7071067811865476f));
}

__device__ __forceinline__ unsigned short f2b(float f) {
    union { float f; unsigned int u; } v; v.f = f;
    unsigned int r = (v.u + 0x7FFFu + ((v.u >> 16) & 1u)) >> 16;
    return (unsigned short)r;
}

// ---------------- Kernel A: transpose [B,C,S] -> [B,S,C] + LayerNorm1 ----------------
__global__ __launch_bounds__(256) void ln1_transpose(
    const float* __restrict__ x, const float* __restrict__ w, const float* __restrict__ bb,
    float* __restrict__ xl, float* __restrict__ t)
{
    __shared__ float tile[128][65];
    __shared__ float mu[64], rs[64];
    const int b = blockIdx.y;
    const int s0 = blockIdx.x * 64;
    const float* xb = x + (size_t)b * CNUM * S;
    for (int i = threadIdx.x; i < 128 * 64; i += 256) {
        int c = i >> 6, sl = i & 63;
        tile[c][sl] = xb[(size_t)c * S + s0 + sl];
    }
    __syncthreads();
    if (threadIdx.x < 64) {
        float sum = 0.f, sq = 0.f;
        for (int c = 0; c < 128; ++c) {
            float v = tile[c][threadIdx.x];
            sum += v; sq += v * v;
        }
        float m = sum * (1.f / 128.f);
        float var = sq * (1.f / 128.f) - m * m;
        mu[threadIdx.x] = m;
        rs[threadIdx.x] = rsqrtf(var + EPSLN);
    }
    __syncthreads();
    for (int i = threadIdx.x; i < 128 * 64; i += 256) {
        int c = i & 127, sl = i >> 7;
        float v = tile[c][sl];
        size_t idx = ((size_t)b * S + s0 + sl) * CNUM + c;
        t[idx] = v;
        xl[idx] = (v - mu[sl]) * rs[sl] * w[c] + bb[c];
    }
}

// ---------------- Generic fp32 GEMM: C = A[M,K] @ B[K,N] + bias, epilogues ----------------
// epi: 0=bias fp32; 1=bias+gelu; 2=bias+res; 3=gelu(bias)+res; 4=bias->bf16; 5=bias->bf16 transposed per-batch (Vt)
__global__ __launch_bounds__(256) void gemm64(
    const float* __restrict__ A, const float* __restrict__ Bw,
    const float* __restrict__ bias, const float* __restrict__ res,
    void* __restrict__ Cv, int M, int N, int K, int epi)
{
    __shared__ float As[16][65];
    __shared__ float Bs[16][65];
    const int bm = blockIdx.y * 64;
    const int bn = blockIdx.x * 64;
    const int tid = threadIdx.x;
    const int tx = tid & 15, ty = tid >> 4;
    float acc[4][4] = {};
    for (int k0 = 0; k0 < K; k0 += 16) {
        #pragma unroll
        for (int i = 0; i < 4; ++i) {
            int idx = tid + i * 256;
            int r = idx >> 4, c = idx & 15;
            As[c][r] = A[(size_t)(bm + r) * K + k0 + c];
        }
        #pragma unroll
        for (int i = 0; i < 4; ++i) {
            int idx = tid + i * 256;
            int r = idx >> 6, c = idx & 63;
            Bs[r][c] = Bw[(size_t)(k0 + r) * N + bn + c];
        }
        __syncthreads();
        #pragma unroll
        for (int kk = 0; kk < 16; ++kk) {
            float a[4], bvec[4];
            #pragma unroll
            for (int i = 0; i < 4; ++i) a[i] = As[kk][ty * 4 + i];
            #pragma unroll
            for (int j = 0; j < 4; ++j) bvec[j] = Bs[kk][tx * 4 + j];
            #pragma unroll
            for (int i = 0; i < 4; ++i)
                #pragma unroll
                for (int j = 0; j < 4; ++j)
                    acc[i][j] += a[i] * bvec[j];
        }
        __syncthreads();
    }
    #pragma unroll
    for (int i = 0; i < 4; ++i) {
        int row = bm + ty * 4 + i;
        #pragma unroll
        for (int j = 0; j < 4; ++j) {
            int col = bn + tx * 4 + j;
            float v = acc[i][j] + bias[col];
            if (epi == 1) v = gelu_exact(v);
            else if (epi == 2) v += res[(size_t)row * N + col];
            else if (epi == 3) v = gelu_exact(v) + res[(size_t)row * N + col];
            if (epi == 4) {
                ((unsigned short*)Cv)[(size_t)row * N + col] = f2b(v);
            } else if (epi == 5) {
                int bt = row >> 12, s = row & 4095;
                ((unsigned short*)Cv)[((size_t)bt * CNUM + col) * S + s] = f2b(v);
            } else {
                ((float*)Cv)[(size_t)row * N + col] = v;
            }
        }
    }
}

// ---------------- Scores via MFMA: Sc[q,k] = SCALE * sum_c Q[q,c]*K[k,c] ----------------
__global__ __launch_bounds__(256) void scores_mfma(
    const unsigned short* __restrict__ Q, const unsigned short* __restrict__ Km,
    float* __restrict__ Sc)
{
    __shared__ unsigned short Qs[128 * 128];
    __shared__ unsigned short Ks[128 * 128];
    const int bm = blockIdx.y * 128;
    const int bn = blockIdx.x * 128;
    const int tid = threadIdx.x;
    const int w = tid >> 6, l = tid & 63;
    const int wr = (w >> 1) * 64, wc = (w & 1) * 64;

    // stage both tiles, 16B-chunk XOR swizzle: chunk c of row r stored at p = c ^ (r&15)
    #pragma unroll
    for (int i = 0; i < 8; ++i) {
        int cid = i * 256 + tid;           // 0..2047
        int r = cid >> 4, c = cid & 15;
        int p = c ^ (r & 15);
        *(ulonglong2*)(Qs + r * 128 + p * 8) =
            *(const ulonglong2*)(Q + (size_t)(bm + r) * 128 + c * 8);
        *(ulonglong2*)(Ks + r * 128 + p * 8) =
            *(const ulonglong2*)(Km + (size_t)(bn + r) * 128 + c * 8);
    }
    __syncthreads();

    f32x4 zero = {0.f, 0.f, 0.f, 0.f};
    f32x4 acc[4][4];
    #pragma unroll
    for (int i = 0; i < 4; ++i)
        #pragma unroll
        for (int j = 0; j < 4; ++j) acc[i][j] = zero;

    #pragma unroll
    for (int ks = 0; ks < 4; ++ks) {
        bf16x8 a[4], b[4];
        #pragma unroll
        for (int i = 0; i < 4; ++i) {
            int m = wr + i * 16 + (l & 15);
            int c_lin = ks * 4 + (l >> 4);
            int p = c_lin ^ (m & 15);
            a[i] = *(const bf16x8*)(Qs + m * 128 + p * 8);
        }
        #pragma unroll
        for (int j = 0; j < 4; ++j) {
            int n = wc + j * 16 + (l & 15);
            int c_lin = ks * 4 + (l >> 4);
            int p = c_lin ^ (n & 15);
            b[j] = *(const bf16x8*)(Ks + n * 128 + p * 8);
        }
        #pragma unroll
        for (int i = 0; i < 4; ++i)
            #pragma unroll
            for (int j = 0; j < 4; ++j)
                acc[i][j] = __builtin_amdgcn_mfma_f32_16x16x32_bf16(a[i], b[j], acc[i][j], 0, 0, 0);
    }

    #pragma unroll
    for (int i = 0; i < 4; ++i) {
        #pragma unroll
        for (int j = 0; j < 4; ++j) {
            int col = bn + wc + j * 16 + (l & 15);
            #pragma unroll
            for (int reg = 0; reg < 4; ++reg) {
                int row = bm + wr + i * 16 + (l >> 4) * 4 + reg;
                Sc[(size_t)row * S + col] = acc[i][j][reg] * SCALE;
            }
        }
    }
}

// ---------------- Column-softmax stats over the QUERY axis (rows of Sc) ----------------
__global__ __launch_bounds__(256) void colstat1(
    const float* __restrict__ Sc, float* __restrict__ pm, float* __restrict__ pl)
{
    int col = blockIdx.x * 256 + threadIdx.x;
    int r0 = blockIdx.y * 256;
    float m = -INFINITY, l = 0.f;
    for (int r = r0; r < r0 + 256; ++r) {
        float v = Sc[(size_t)r * S + col];
        if (v > m) { l = l * __expf(m - v) + 1.f; m = v; }
        else l += __expf(v - m);
    }
    pm[(size_t)blockIdx.y * S + col] = m;
    pl[(size_t)blockIdx.y * S + col] = l;
}

__global__ __launch_bounds__(256) void colstat2(
    const float* __restrict__ pm, const float* __restrict__ pl,
    float* __restrict__ mcol, float* __restrict__ rl)
{
    int col = blockIdx.x * 256 + threadIdx.x;
    float M = -INFINITY;
    for (int i = 0; i < 16; ++i) M = fmaxf(M, pm[(size_t)i * S + col]);
    float L = 0.f;
    for (int i = 0; i < 16; ++i) L += pl[(size_t)i * S + col] * __expf(pm[(size_t)i * S + col] - M);
    mcol[col] = M;
    rl[col] = 1.0f / L;
}

// ---------------- attn@V via MFMA, split-K=16, atomicAdd epilogue ----------------
#define KCH 256
__global__ __launch_bounds__(256) void attnv_mfma(
    const float* __restrict__ Sc, const float* __restrict__ mcol,
    const float* __restrict__ rl, const unsigned short* __restrict__ Vt,
    float* __restrict__ O)
{
    __shared__ unsigned short Vs[128 * KCH];  // 64KB: Vt chunk, row=c (0..127), swizzled 16B chunks
    __shared__ unsigned short Ps[128 * 32];   // 8KB: P tile, row=q-local, 32 k
    const int bq = blockIdx.y * 128;
    const int kbase = blockIdx.x * KCH;
    const int tid = threadIdx.x;
    const int w = tid >> 6, l = tid & 63;
    const int wr = (w >> 1) * 64, wc = (w & 1) * 64;

    // stage Vs: 128 rows x 256 bf16 = 4096 chunks of 16B; p = c ^ (r&15)
    #pragma unroll
    for (int i = 0; i < 16; ++i) {
        int cid = i * 256 + tid;
        int r = cid >> 5, c = cid & 31;
        int p = c ^ (r & 15);
        *(ulonglong2*)(Vs + r * KCH + p * 8) =
            *(const ulonglong2*)(Vt + (size_t)r * S + kbase + c * 8);
    }

    f32x4 zero = {0.f, 0.f, 0.f, 0.f};
    f32x4 acc[4][4];
    #pragma unroll
    for (int i = 0; i < 4; ++i)
        #pragma unroll
        for (int j = 0; j < 4; ++j) acc[i][j] = zero;

    for (int ks = 0; ks < KCH / 32; ++ks) {
        __syncthreads();   // Vs visible (first iter); Ps reads of prev iter done
        // stage P: 128 q-rows x 32 k, exp applied; chunk pos = ch ^ ((r>>1)&3)
        #pragma unroll
        for (int i = 0; i < 16; ++i) {
            int eid = i * 256 + tid;       // 0..4095
            int r = eid >> 5, c = eid & 31;
            int kk = kbase + ks * 32 + c;
            float s = Sc[(size_t)(bq + r) * S + kk];
            float pval = __expf(s - mcol[kk]) * rl[kk];
            int ch = c >> 3;
            int pch = ch ^ ((r >> 1) & 3);
            Ps[r * 32 + pch * 8 + (c & 7)] = f2b(pval);
        }
        __syncthreads();

        bf16x8 a[4], b[4];
        #pragma unroll
        for (int i = 0; i < 4; ++i) {
            int m = wr + i * 16 + (l & 15);
            int ch = l >> 4;
            int pch = ch ^ ((m >> 1) & 3);
            a[i] = *(const bf16x8*)(Ps + m * 32 + pch * 8);
        }
        #pragma unroll
        for (int j = 0; j < 4; ++j) {
            int n = wc + j * 16 + (l & 15);
            int c_lin = ks * 4 + (l >> 4);
            int p = c_lin ^ (n & 15);
            b[j] = *(const bf16x8*)(Vs + n * KCH + p * 8);
        }
        #pragma unroll
        for (int i = 0; i < 4; ++i)
            #pragma unroll
            for (int j = 0; j < 4; ++j)
                acc[i][j] = __builtin_amdgcn_mfma_f32_16x16x32_bf16(a[i], b[j], acc[i][j], 0, 0, 0);
    }

    #pragma unroll
    for (int i = 0; i < 4; ++i) {
        #pragma unroll
        for (int j = 0; j < 4; ++j) {
            int col = wc + j * 16 + (l & 15);
            #pragma unroll
            for (int reg = 0; reg < 4; ++reg) {
                int row = bq + wr + i * 16 + (l >> 4) * 4 + reg;
                atomicAdd(&O[(size_t)row * CNUM + col], acc[i][j][reg]);
            }
        }
    }
}

// ---------------- LayerNorm over rows of [M,128]: one wave per row ----------------
__global__ __launch_bounds__(256) void ln_rows(
    const float* __restrict__ y, const float* __restrict__ w, const float* __restrict__ bb,
    float* __restrict__ z)
{
    int row = blockIdx.x * 4 + (threadIdx.x >> 6);
    int lane = threadIdx.x & 63;
    const float* yr = y + (size_t)row * CNUM;
    float v0 = yr[lane], v1 = yr[lane + 64];
    float sum = v0 + v1, sq = v0 * v0 + v1 * v1;
    #pragma unroll
    for (int off = 32; off; off >>= 1) {
        sum += __shfl_xor(sum, off);
        sq  += __shfl_xor(sq, off);
    }
    float mean = sum * (1.f / 128.f);
    float var = sq * (1.f / 128.f) - mean * mean;
    float r = rsqrtf(var + EPSLN);
    z[(size_t)row * CNUM + lane]      = (v0 - mean) * r * w[lane] + bb[lane];
    z[(size_t)row * CNUM + lane + 64] = (v1 - mean) * r * w[lane + 64] + bb[lane + 64];
}

// ---------------- Final transpose [B,S,C] -> [B,C,S] ----------------
__global__ void transpose_out(const float* __restrict__ tf, float* __restrict__ out)
{
    __shared__ float tile[32][33];
    const int b = blockIdx.z;
    const int s0 = blockIdx.x * 32, c0 = blockIdx.y * 32;
    for (int i = threadIdx.y; i < 32; i += 8)
        tile[i][threadIdx.x] = tf[((size_t)b * S + s0 + i) * CNUM + c0 + threadIdx.x];
    __syncthreads();
    for (int i = threadIdx.y; i < 32; i += 8)
        out[((size_t)b * CNUM + c0 + i) * S + s0 + threadIdx.x] = tile[threadIdx.x][i];
}

extern "C" void kernel_launch(void* const* d_in, const int* in_sizes, int n_in,
                              void* d_out, int out_size, void* d_ws, size_t ws_size,
                              hipStream_t stream)
{
    (void)in_sizes; (void)n_in; (void)out_size; (void)ws_size;
    const float* x    = (const float*)d_in[0];
    const float* ln1w = (const float*)d_in[1];
    const float* ln1b = (const float*)d_in[2];
    const float* wq   = (const float*)d_in[3];
    const float* bq   = (const float*)d_in[4];
    const float* wk   = (const float*)d_in[5];
    const float* bk   = (const float*)d_in[6];
    const float* wv   = (const float*)d_in[7];
    const float* bv   = (const float*)d_in[8];
    const float* wo   = (const float*)d_in[9];
    const float* bo   = (const float*)d_in[10];
    const float* ln2w = (const float*)d_in[11];
    const float* ln2b = (const float*)d_in[12];
    const float* w1   = (const float*)d_in[13];
    const float* b1   = (const float*)d_in[14];
    const float* w2   = (const float*)d_in[15];
    const float* b2   = (const float*)d_in[16];
    float* out = (float*)d_out;

    float* ws = (float*)d_ws;
    const size_t NSC = (size_t)BATCH * S * CNUM;   // 2,097,152
    float* xl     = ws;                  // reused as z (LN2 out)
    float* t      = xl + NSC;
    float* attout = t + NSC;             // reused as tf
    float* y      = attout + NSC;
    float* Sc     = y + NSC;             // 16,777,216 floats; reused as MLP hidden h
    float* pm     = Sc + (size_t)S * S;
    float* pl     = pm + 16 * S;
    float* mcol   = pl + 16 * S;
    float* rlc    = mcol + S;
    unsigned short* qh = (unsigned short*)(rlc + S);              // [B,S,C] bf16
    unsigned short* kh = qh + NSC;
    unsigned short* Vt = kh + NSC;                                // [B,C,S] bf16

    const int M = BATCH * S;             // 16384

    ln1_transpose<<<dim3(S / 64, BATCH), 256, 0, stream>>>(x, ln1w, ln1b, xl, t);

    gemm64<<<dim3(2, M / 64), 256, 0, stream>>>(xl, wq, bq, nullptr, qh, M, 128, 128, 4);
    gemm64<<<dim3(2, M / 64), 256, 0, stream>>>(xl, wk, bk, nullptr, kh, M, 128, 128, 4);
    gemm64<<<dim3(2, M / 64), 256, 0, stream>>>(xl, wv, bv, nullptr, Vt, M, 128, 128, 5);

    hipMemsetAsync(attout, 0, NSC * sizeof(float), stream);

    for (int b = 0; b < BATCH; ++b) {
        const unsigned short* qb = qh + (size_t)b * S * CNUM;
        const unsigned short* kb = kh + (size_t)b * S * CNUM;
        const unsigned short* vb = Vt + (size_t)b * S * CNUM;
        float* ob = attout + (size_t)b * S * CNUM;
        scores_mfma<<<dim3(S / 128, S / 128), 256, 0, stream>>>(qb, kb, Sc);
        colstat1<<<dim3(S / 256, 16), 256, 0, stream>>>(Sc, pm, pl);
        colstat2<<<dim3(S / 256), 256, 0, stream>>>(pm, pl, mcol, rlc);
        attnv_mfma<<<dim3(S / KCH, S / 128), 256, 0, stream>>>(Sc, mcol, rlc, vb, ob);
    }

    // y = attout @ wo + bo + t
    gemm64<<<dim3(2, M / 64), 256, 0, stream>>>(attout, wo, bo, t, y, M, 128, 128, 2);
    // z = LN2(y)   (z aliases xl)
    ln_rows<<<M / 4, 256, 0, stream>>>(y, ln2w, ln2b, xl);
    // h = gelu(z @ w1 + b1)   (h aliases Sc)
    gemm64<<<dim3(4, M / 64), 256, 0, stream>>>(xl, w1, b1, nullptr, Sc, M, 256, 128, 1);
    // tf = gelu(h @ w2 + b2) + y   (tf aliases attout)
    gemm64<<<dim3(2, M / 64), 256, 0, stream>>>(Sc, w2, b2, y, attout, M, 128, 256, 3);
    // out = transpose(tf)
    transpose_out<<<dim3(S / 32, CNUM / 32, BATCH), dim3(32, 8), 0, stream>>>(attout, out);
}

// Round 3
// 557.841 us; speedup vs baseline: 2.5115x; 1.4121x over previous
//
#include <hip/hip_runtime.h>
#include <math.h>

#define S 4096
#define CNUM 128
#define BATCH 4
#define SCALE 0.25f
#define EPSLN 1e-5f

typedef __attribute__((ext_vector_type(8))) short bf16x8;
typedef __attribute__((ext_vector_type(4))) float f32x4;

__device__ __forceinline__ float gelu_exact(float x) {
    return 0.5f * x * (1.0f + erff(x * 0.7071067811865476f));
}

__device__ __forceinline__ unsigned short f2b(float f) {
    union { float f; unsigned int u; } v; v.f = f;
    unsigned int r = (v.u + 0x7FFFu + ((v.u >> 16) & 1u)) >> 16;
    return (unsigned short)r;
}

// order-preserving float<->uint for atomicMax
__device__ __forceinline__ unsigned fenc(float f) {
    unsigned u = __float_as_uint(f);
    return (u & 0x80000000u) ? ~u : (u | 0x80000000u);
}
__device__ __forceinline__ float fdec(unsigned e) {
    unsigned u = (e & 0x80000000u) ? (e ^ 0x80000000u) : ~e;
    return __uint_as_float(u);
}

// ---------------- Kernel A: transpose [B,C,S] -> [B,S,C] + LayerNorm1 ----------------
__global__ __launch_bounds__(256) void ln1_transpose(
    const float* __restrict__ x, const float* __restrict__ w, const float* __restrict__ bb,
    float* __restrict__ xl, float* __restrict__ t)
{
    __shared__ float tile[128][65];
    __shared__ float mu[64], rs[64];
    const int b = blockIdx.y;
    const int s0 = blockIdx.x * 64;
    const float* xb = x + (size_t)b * CNUM * S;
    for (int i = threadIdx.x; i < 128 * 64; i += 256) {
        int c = i >> 6, sl = i & 63;
        tile[c][sl] = xb[(size_t)c * S + s0 + sl];
    }
    __syncthreads();
    if (threadIdx.x < 64) {
        float sum = 0.f, sq = 0.f;
        for (int c = 0; c < 128; ++c) {
            float v = tile[c][threadIdx.x];
            sum += v; sq += v * v;
        }
        float m = sum * (1.f / 128.f);
        float var = sq * (1.f / 128.f) - m * m;
        mu[threadIdx.x] = m;
        rs[threadIdx.x] = rsqrtf(var + EPSLN);
    }
    __syncthreads();
    for (int i = threadIdx.x; i < 128 * 64; i += 256) {
        int c = i & 127, sl = i >> 7;
        float v = tile[c][sl];
        size_t idx = ((size_t)b * S + s0 + sl) * CNUM + c;
        t[idx] = v;
        xl[idx] = (v - mu[sl]) * rs[sl] * w[c] + bb[c];
    }
}

// ---------------- Generic fp32 GEMM: C = A[M,K] @ B[K,N] + bias, epilogues ----------------
// epi: 0=bias fp32; 1=bias+gelu; 2=bias+res; 3=gelu(bias)+res; 4=bias->bf16; 5=bias->bf16 transposed per-batch (Vt)
__global__ __launch_bounds__(256) void gemm64(
    const float* __restrict__ A, const float* __restrict__ Bw,
    const float* __restrict__ bias, const float* __restrict__ res,
    void* __restrict__ Cv, int M, int N, int K, int epi)
{
    __shared__ float As[16][65];
    __shared__ float Bs[16][65];
    const int bm = blockIdx.y * 64;
    const int bn = blockIdx.x * 64;
    const int tid = threadIdx.x;
    const int tx = tid & 15, ty = tid >> 4;
    float acc[4][4] = {};
    for (int k0 = 0; k0 < K; k0 += 16) {
        #pragma unroll
        for (int i = 0; i < 4; ++i) {
            int idx = tid + i * 256;
            int r = idx >> 4, c = idx & 15;
            As[c][r] = A[(size_t)(bm + r) * K + k0 + c];
        }
        #pragma unroll
        for (int i = 0; i < 4; ++i) {
            int idx = tid + i * 256;
            int r = idx >> 6, c = idx & 63;
            Bs[r][c] = Bw[(size_t)(k0 + r) * N + bn + c];
        }
        __syncthreads();
        #pragma unroll
        for (int kk = 0; kk < 16; ++kk) {
            float a[4], bvec[4];
            #pragma unroll
            for (int i = 0; i < 4; ++i) a[i] = As[kk][ty * 4 + i];
            #pragma unroll
            for (int j = 0; j < 4; ++j) bvec[j] = Bs[kk][tx * 4 + j];
            #pragma unroll
            for (int i = 0; i < 4; ++i)
                #pragma unroll
                for (int j = 0; j < 4; ++j)
                    acc[i][j] += a[i] * bvec[j];
        }
        __syncthreads();
    }
    #pragma unroll
    for (int i = 0; i < 4; ++i) {
        int row = bm + ty * 4 + i;
        #pragma unroll
        for (int j = 0; j < 4; ++j) {
            int col = bn + tx * 4 + j;
            float v = acc[i][j] + bias[col];
            if (epi == 1) v = gelu_exact(v);
            else if (epi == 2) v += res[(size_t)row * N + col];
            else if (epi == 3) v = gelu_exact(v) + res[(size_t)row * N + col];
            if (epi == 4) {
                ((unsigned short*)Cv)[(size_t)row * N + col] = f2b(v);
            } else if (epi == 5) {
                int bt = row >> 12, s = row & 4095;
                ((unsigned short*)Cv)[((size_t)bt * CNUM + col) * S + s] = f2b(v);
            } else {
                ((float*)Cv)[(size_t)row * N + col] = v;
            }
        }
    }
}

// ---------------- Scores via MFMA + fused column-max atomics ----------------
__global__ __launch_bounds__(256) void scores_mfma(
    const unsigned short* __restrict__ Q, const unsigned short* __restrict__ Km,
    float* __restrict__ Sc, unsigned* __restrict__ gmax)
{
    __shared__ unsigned short Qs[128 * 128];
    __shared__ unsigned short Ks[128 * 128];
    __shared__ float cmax[2][128];
    const int bm = blockIdx.y * 128;
    const int bn = blockIdx.x * 128;
    const int tid = threadIdx.x;
    const int w = tid >> 6, l = tid & 63;
    const int wr = (w >> 1) * 64, wc = (w & 1) * 64;

    #pragma unroll
    for (int i = 0; i < 8; ++i) {
        int cid = i * 256 + tid;           // 0..2047
        int r = cid >> 4, c = cid & 15;
        int p = c ^ (r & 15);
        *(ulonglong2*)(Qs + r * 128 + p * 8) =
            *(const ulonglong2*)(Q + (size_t)(bm + r) * 128 + c * 8);
        *(ulonglong2*)(Ks + r * 128 + p * 8) =
            *(const ulonglong2*)(Km + (size_t)(bn + r) * 128 + c * 8);
    }
    __syncthreads();

    f32x4 zero = {0.f, 0.f, 0.f, 0.f};
    f32x4 acc[4][4];
    #pragma unroll
    for (int i = 0; i < 4; ++i)
        #pragma unroll
        for (int j = 0; j < 4; ++j) acc[i][j] = zero;

    #pragma unroll
    for (int ks = 0; ks < 4; ++ks) {
        bf16x8 a[4], b[4];
        #pragma unroll
        for (int i = 0; i < 4; ++i) {
            int m = wr + i * 16 + (l & 15);
            int c_lin = ks * 4 + (l >> 4);
            int p = c_lin ^ (m & 15);
            a[i] = *(const bf16x8*)(Qs + m * 128 + p * 8);
        }
        #pragma unroll
        for (int j = 0; j < 4; ++j) {
            int n = wc + j * 16 + (l & 15);
            int c_lin = ks * 4 + (l >> 4);
            int p = c_lin ^ (n & 15);
            b[j] = *(const bf16x8*)(Ks + n * 128 + p * 8);
        }
        #pragma unroll
        for (int i = 0; i < 4; ++i)
            #pragma unroll
            for (int j = 0; j < 4; ++j)
                acc[i][j] = __builtin_amdgcn_mfma_f32_16x16x32_bf16(a[i], b[j], acc[i][j], 0, 0, 0);
    }

    // write Sc (scaled) and reduce per-column max
    float jmax[4];
    #pragma unroll
    for (int j = 0; j < 4; ++j) jmax[j] = -INFINITY;
    #pragma unroll
    for (int i = 0; i < 4; ++i) {
        #pragma unroll
        for (int j = 0; j < 4; ++j) {
            int col = bn + wc + j * 16 + (l & 15);
            #pragma unroll
            for (int reg = 0; reg < 4; ++reg) {
                int row = bm + wr + i * 16 + (l >> 4) * 4 + reg;
                float sv = acc[i][j][reg] * SCALE;
                Sc[(size_t)row * S + col] = sv;
                jmax[j] = fmaxf(jmax[j], sv);
            }
        }
    }
    // reduce across the 4 quad-groups (same col, different rows): lanes l, l^16, l^32
    #pragma unroll
    for (int j = 0; j < 4; ++j) {
        jmax[j] = fmaxf(jmax[j], __shfl_xor(jmax[j], 16));
        jmax[j] = fmaxf(jmax[j], __shfl_xor(jmax[j], 32));
    }
    if (l < 16) {
        #pragma unroll
        for (int j = 0; j < 4; ++j)
            cmax[w >> 1][wc + j * 16 + l] = jmax[j];
    }
    __syncthreads();
    if (tid < 128) {
        float m = fmaxf(cmax[0][tid], cmax[1][tid]);
        atomicMax(gmax + bn + tid, fenc(m));
    }
}

// ---------------- Column sum of exp with known max (partials over 64-row chunks) ----------------
__global__ __launch_bounds__(256) void colsum(
    const float* __restrict__ Sc, const unsigned* __restrict__ gmax, float* __restrict__ pl)
{
    int col = blockIdx.x * 256 + threadIdx.x;
    int r0 = blockIdx.y * 64;
    float M = fdec(gmax[col]);
    float acc[8] = {};
    #pragma unroll
    for (int r = 0; r < 64; ++r)
        acc[r & 7] += __expf(Sc[(size_t)(r0 + r) * S + col] - M);
    float s = ((acc[0] + acc[1]) + (acc[2] + acc[3])) + ((acc[4] + acc[5]) + (acc[6] + acc[7]));
    pl[(size_t)blockIdx.y * S + col] = s;
}

__global__ __launch_bounds__(256) void colfin(
    const unsigned* __restrict__ gmax, const float* __restrict__ pl,
    float* __restrict__ mcol, float* __restrict__ rl)
{
    int col = blockIdx.x * 256 + threadIdx.x;
    float L = 0.f;
    for (int i = 0; i < 64; ++i) L += pl[(size_t)i * S + col];
    mcol[col] = fdec(gmax[col]);
    rl[col] = 1.0f / L;
}

// ---------------- attn@V via MFMA, split-K=16, atomicAdd epilogue ----------------
#define KCH 256
__global__ __launch_bounds__(256) void attnv_mfma(
    const float* __restrict__ Sc, const float* __restrict__ mcol,
    const float* __restrict__ rl, const unsigned short* __restrict__ Vt,
    float* __restrict__ O)
{
    __shared__ unsigned short Vs[128 * KCH];  // 64KB
    __shared__ unsigned short Ps[128 * 32];   // 8KB
    const int bq = blockIdx.y * 128;
    const int kbase = blockIdx.x * KCH;
    const int tid = threadIdx.x;
    const int w = tid >> 6, l = tid & 63;
    const int wr = (w >> 1) * 64, wc = (w & 1) * 64;

    #pragma unroll
    for (int i = 0; i < 16; ++i) {
        int cid = i * 256 + tid;
        int r = cid >> 5, c = cid & 31;
        int p = c ^ (r & 15);
        *(ulonglong2*)(Vs + r * KCH + p * 8) =
            *(const ulonglong2*)(Vt + (size_t)r * S + kbase + c * 8);
    }

    f32x4 zero = {0.f, 0.f, 0.f, 0.f};
    f32x4 acc[4][4];
    #pragma unroll
    for (int i = 0; i < 4; ++i)
        #pragma unroll
        for (int j = 0; j < 4; ++j) acc[i][j] = zero;

    for (int ks = 0; ks < KCH / 32; ++ks) {
        __syncthreads();
        #pragma unroll
        for (int i = 0; i < 16; ++i) {
            int eid = i * 256 + tid;       // 0..4095
            int r = eid >> 5, c = eid & 31;
            int kk = kbase + ks * 32 + c;
            float s = Sc[(size_t)(bq + r) * S + kk];
            float pval = __expf(s - mcol[kk]) * rl[kk];
            int ch = c >> 3;
            int pch = ch ^ ((r >> 1) & 3);
            Ps[r * 32 + pch * 8 + (c & 7)] = f2b(pval);
        }
        __syncthreads();

        bf16x8 a[4], b[4];
        #pragma unroll
        for (int i = 0; i < 4; ++i) {
            int m = wr + i * 16 + (l & 15);
            int ch = l >> 4;
            int pch = ch ^ ((m >> 1) & 3);
            a[i] = *(const bf16x8*)(Ps + m * 32 + pch * 8);
        }
        #pragma unroll
        for (int j = 0; j < 4; ++j) {
            int n = wc + j * 16 + (l & 15);
            int c_lin = ks * 4 + (l >> 4);
            int p = c_lin ^ (n & 15);
            b[j] = *(const bf16x8*)(Vs + n * KCH + p * 8);
        }
        #pragma unroll
        for (int i = 0; i < 4; ++i)
            #pragma unroll
            for (int j = 0; j < 4; ++j)
                acc[i][j] = __builtin_amdgcn_mfma_f32_16x16x32_bf16(a[i], b[j], acc[i][j], 0, 0, 0);
    }

    #pragma unroll
    for (int i = 0; i < 4; ++i) {
        #pragma unroll
        for (int j = 0; j < 4; ++j) {
            int col = wc + j * 16 + (l & 15);
            #pragma unroll
            for (int reg = 0; reg < 4; ++reg) {
                int row = bq + wr + i * 16 + (l >> 4) * 4 + reg;
                atomicAdd(&O[(size_t)row * CNUM + col], acc[i][j][reg]);
            }
        }
    }
}

// ---------------- LayerNorm over rows of [M,128]: one wave per row ----------------
__global__ __launch_bounds__(256) void ln_rows(
    const float* __restrict__ y, const float* __restrict__ w, const float* __restrict__ bb,
    float* __restrict__ z)
{
    int row = blockIdx.x * 4 + (threadIdx.x >> 6);
    int lane = threadIdx.x & 63;
    const float* yr = y + (size_t)row * CNUM;
    float v0 = yr[lane], v1 = yr[lane + 64];
    float sum = v0 + v1, sq = v0 * v0 + v1 * v1;
    #pragma unroll
    for (int off = 32; off; off >>= 1) {
        sum += __shfl_xor(sum, off);
        sq  += __shfl_xor(sq, off);
    }
    float mean = sum * (1.f / 128.f);
    float var = sq * (1.f / 128.f) - mean * mean;
    float r = rsqrtf(var + EPSLN);
    z[(size_t)row * CNUM + lane]      = (v0 - mean) * r * w[lane] + bb[lane];
    z[(size_t)row * CNUM + lane + 64] = (v1 - mean) * r * w[lane + 64] + bb[lane + 64];
}

// ---------------- Final transpose [B,S,C] -> [B,C,S] ----------------
__global__ void transpose_out(const float* __restrict__ tf, float* __restrict__ out)
{
    __shared__ float tile[32][33];
    const int b = blockIdx.z;
    const int s0 = blockIdx.x * 32, c0 = blockIdx.y * 32;
    for (int i = threadIdx.y; i < 32; i += 8)
        tile[i][threadIdx.x] = tf[((size_t)b * S + s0 + i) * CNUM + c0 + threadIdx.x];
    __syncthreads();
    for (int i = threadIdx.y; i < 32; i += 8)
        out[((size_t)b * CNUM + c0 + i) * S + s0 + threadIdx.x] = tile[threadIdx.x][i];
}

extern "C" void kernel_launch(void* const* d_in, const int* in_sizes, int n_in,
                              void* d_out, int out_size, void* d_ws, size_t ws_size,
                              hipStream_t stream)
{
    (void)in_sizes; (void)n_in; (void)out_size; (void)ws_size;
    const float* x    = (const float*)d_in[0];
    const float* ln1w = (const float*)d_in[1];
    const float* ln1b = (const float*)d_in[2];
    const float* wq   = (const float*)d_in[3];
    const float* bq   = (const float*)d_in[4];
    const float* wk   = (const float*)d_in[5];
    const float* bk   = (const float*)d_in[6];
    const float* wv   = (const float*)d_in[7];
    const float* bv   = (const float*)d_in[8];
    const float* wo   = (const float*)d_in[9];
    const float* bo   = (const float*)d_in[10];
    const float* ln2w = (const float*)d_in[11];
    const float* ln2b = (const float*)d_in[12];
    const float* w1   = (const float*)d_in[13];
    const float* b1   = (const float*)d_in[14];
    const float* w2   = (const float*)d_in[15];
    const float* b2   = (const float*)d_in[16];
    float* out = (float*)d_out;

    float* ws = (float*)d_ws;
    const size_t NSC = (size_t)BATCH * S * CNUM;   // 2,097,152
    float* xl     = ws;                  // reused as z (LN2 out)
    float* t      = xl + NSC;
    float* attout = t + NSC;             // reused as tf
    float* y      = attout + NSC;
    float* Sc     = y + NSC;             // 16,777,216 floats; reused as MLP hidden h
    float* pl     = Sc + (size_t)S * S;  // 64*S partials
    unsigned* gmax = (unsigned*)(pl + 64 * S);
    float* mcol   = (float*)(gmax + S);
    float* rlc    = mcol + S;
    unsigned short* qh = (unsigned short*)(rlc + S);              // [B,S,C] bf16
    unsigned short* kh = qh + NSC;
    unsigned short* Vt = kh + NSC;                                // [B,C,S] bf16

    const int M = BATCH * S;             // 16384

    ln1_transpose<<<dim3(S / 64, BATCH), 256, 0, stream>>>(x, ln1w, ln1b, xl, t);

    gemm64<<<dim3(2, M / 64), 256, 0, stream>>>(xl, wq, bq, nullptr, qh, M, 128, 128, 4);
    gemm64<<<dim3(2, M / 64), 256, 0, stream>>>(xl, wk, bk, nullptr, kh, M, 128, 128, 4);
    gemm64<<<dim3(2, M / 64), 256, 0, stream>>>(xl, wv, bv, nullptr, Vt, M, 128, 128, 5);

    hipMemsetAsync(attout, 0, NSC * sizeof(float), stream);

    for (int b = 0; b < BATCH; ++b) {
        const unsigned short* qb = qh + (size_t)b * S * CNUM;
        const unsigned short* kb = kh + (size_t)b * S * CNUM;
        const unsigned short* vb = Vt + (size_t)b * S * CNUM;
        float* ob = attout + (size_t)b * S * CNUM;
        hipMemsetAsync(gmax, 0, S * sizeof(unsigned), stream);
        scores_mfma<<<dim3(S / 128, S / 128), 256, 0, stream>>>(qb, kb, Sc, gmax);
        colsum<<<dim3(S / 256, 64), 256, 0, stream>>>(Sc, gmax, pl);
        colfin<<<dim3(S / 256), 256, 0, stream>>>(gmax, pl, mcol, rlc);
        attnv_mfma<<<dim3(S / KCH, S / 128), 256, 0, stream>>>(Sc, mcol, rlc, vb, ob);
    }

    // y = attout @ wo + bo + t
    gemm64<<<dim3(2, M / 64), 256, 0, stream>>>(attout, wo, bo, t, y, M, 128, 128, 2);
    // z = LN2(y)   (z aliases xl)
    ln_rows<<<M / 4, 256, 0, stream>>>(y, ln2w, ln2b, xl);
    // h = gelu(z @ w1 + b1)   (h aliases Sc)
    gemm64<<<dim3(4, M / 64), 256, 0, stream>>>(xl, w1, b1, nullptr, Sc, M, 256, 128, 1);
    // tf = gelu(h @ w2 + b2) + y   (tf aliases attout)
    gemm64<<<dim3(2, M / 64), 256, 0, stream>>>(Sc, w2, b2, y, attout, M, 128, 256, 3);
    // out = transpose(tf)
    transpose_out<<<dim3(S / 32, CNUM / 32, BATCH), dim3(32, 8), 0, stream>>>(attout, out);
}

// Round 4
// 323.319 us; speedup vs baseline: 4.3332x; 1.7254x over previous
//
#include <hip/hip_runtime.h>
#include <math.h>

#define S 4096
#define CNUM 128
#define BATCH 4
#define MTOT (BATCH * S)
#define SCALE 0.25f
#define EPSLN 1e-5f

typedef __attribute__((ext_vector_type(8))) short bf16x8;
typedef __attribute__((ext_vector_type(4))) float f32x4;

__device__ __forceinline__ float gelu_exact(float x) {
    return 0.5f * x * (1.0f + erff(x * 0.7071067811865476f));
}

__device__ __forceinline__ unsigned short f2b(float f) {
    union { float f; unsigned int u; } v; v.f = f;
    unsigned int r = (v.u + 0x7FFFu + ((v.u >> 16) & 1u)) >> 16;
    return (unsigned short)r;
}
__device__ __forceinline__ float b2f(unsigned short u) {
    return __uint_as_float((unsigned)u << 16);
}

// order-preserving float<->uint for atomicMax (memset-0 == -inf sentinel)
__device__ __forceinline__ unsigned fenc(float f) {
    unsigned u = __float_as_uint(f);
    return (u & 0x80000000u) ? ~u : (u | 0x80000000u);
}
__device__ __forceinline__ float fdec(unsigned e) {
    unsigned u = (e & 0x80000000u) ? (e ^ 0x80000000u) : ~e;
    return __uint_as_float(u);
}

// ---------------- transpose [B,C,S] -> [B,S,C]: t fp32 (residual), xlh bf16 (LN1 out) ----------------
__global__ __launch_bounds__(256) void ln1_transpose(
    const float* __restrict__ x, const float* __restrict__ w, const float* __restrict__ bb,
    unsigned short* __restrict__ xlh, float* __restrict__ t)
{
    __shared__ float tile[128][65];
    __shared__ float mu[64], rs[64];
    const int b = blockIdx.y;
    const int s0 = blockIdx.x * 64;
    const float* xb = x + (size_t)b * CNUM * S;
    for (int i = threadIdx.x; i < 128 * 64; i += 256) {
        int c = i >> 6, sl = i & 63;
        tile[c][sl] = xb[(size_t)c * S + s0 + sl];
    }
    __syncthreads();
    if (threadIdx.x < 64) {
        float sum = 0.f, sq = 0.f;
        for (int c = 0; c < 128; ++c) {
            float v = tile[c][threadIdx.x];
            sum += v; sq += v * v;
        }
        float m = sum * (1.f / 128.f);
        float var = sq * (1.f / 128.f) - m * m;
        mu[threadIdx.x] = m;
        rs[threadIdx.x] = rsqrtf(var + EPSLN);
    }
    __syncthreads();
    for (int i = threadIdx.x; i < 128 * 64; i += 256) {
        int c = i & 127, sl = i >> 7;
        float v = tile[c][sl];
        size_t idx = ((size_t)b * S + s0 + sl) * CNUM + c;
        t[idx] = v;
        xlh[idx] = f2b((v - mu[sl]) * rs[sl] * w[c] + bb[c]);
    }
}

// ---------------- weight convert+transpose fp32[K,N] -> bf16[N,K]; biases packed ----------------
__global__ __launch_bounds__(256) void convw(
    const float* __restrict__ wq, const float* __restrict__ wk, const float* __restrict__ wv,
    const float* __restrict__ wo, const float* __restrict__ w1, const float* __restrict__ w2,
    const float* __restrict__ bq, const float* __restrict__ bk, const float* __restrict__ bv,
    unsigned short* __restrict__ wqkvh, unsigned short* __restrict__ woh,
    unsigned short* __restrict__ w1h, unsigned short* __restrict__ w2h,
    float* __restrict__ bqkv)
{
    int a = blockIdx.y;
    int idx = blockIdx.x * 256 + threadIdx.x;
    if (a == 6) {
        if (idx < 128) bqkv[idx] = bq[idx];
        else if (idx < 256) bqkv[idx] = bk[idx - 128];
        else if (idx < 384) bqkv[idx] = bv[idx - 256];
        return;
    }
    const float* src; unsigned short* dst; int Nsh, Ksz;
    switch (a) {
        case 0: src = wq; dst = wqkvh;          Nsh = 7; Ksz = 128; break;
        case 1: src = wk; dst = wqkvh + 16384;  Nsh = 7; Ksz = 128; break;
        case 2: src = wv; dst = wqkvh + 32768;  Nsh = 7; Ksz = 128; break;
        case 3: src = wo; dst = woh;            Nsh = 7; Ksz = 128; break;
        case 4: src = w1; dst = w1h;            Nsh = 8; Ksz = 128; break;
        default: src = w2; dst = w2h;           Nsh = 7; Ksz = 256; break;
    }
    int total = Ksz << Nsh;
    if (idx >= total) return;
    int k = idx >> Nsh, n = idx & ((1 << Nsh) - 1);
    dst[n * Ksz + k] = f2b(src[idx]);
}

// ---------------- MFMA GEMM: C = A[M,KT](bf16) @ Bt[N,KT]^T(bf16) + bias, epilogues ----------------
// epi: 2 = fp32 +res -> C[M,N]
//      6 = gelu -> bf16 C[M,N]
//      7 = QKV combined (z=0,1: bf16 [M,128]; z=2: bf16 Vt[b][col][s])
//      8 = gelu + res -> fp32 out[b][col][s] (fused final transpose)
template<int KT>
__global__ __launch_bounds__(256) void gemm_mfma(
    const unsigned short* __restrict__ A, const unsigned short* __restrict__ Bt,
    const float* __restrict__ bias, const float* __restrict__ res,
    void* __restrict__ Cv, int N, int epi)
{
    constexpr int CH = KT / 8;
    constexpr int CSH = (KT == 128) ? 4 : 5;
    __shared__ unsigned short As[64 * KT];
    __shared__ unsigned short Bs[128 * KT];
    const int bm = blockIdx.y * 64;
    const int bn = blockIdx.x * 128;
    const int z = blockIdx.z;
    const unsigned short* Btz = (epi == 7) ? Bt + z * 16384 : Bt;
    const float* biasz = (epi == 7) ? bias + z * 128 : bias;
    const int tid = threadIdx.x;
    const int w = tid >> 6, l = tid & 63;
    const int rw = (w & 1) * 32, cw = (w >> 1) * 64;

    #pragma unroll
    for (int i = 0; i < (64 * CH) / 256; ++i) {
        int cid = i * 256 + tid;
        int r = cid >> CSH, c = cid & (CH - 1);
        int p = (c & ~15) | ((c ^ r) & 15);
        *(ulonglong2*)(As + r * KT + p * 8) =
            *(const ulonglong2*)(A + (size_t)(bm + r) * KT + c * 8);
    }
    #pragma unroll
    for (int i = 0; i < (128 * CH) / 256; ++i) {
        int cid = i * 256 + tid;
        int r = cid >> CSH, c = cid & (CH - 1);
        int p = (c & ~15) | ((c ^ r) & 15);
        *(ulonglong2*)(Bs + r * KT + p * 8) =
            *(const ulonglong2*)(Btz + (size_t)(bn + r) * KT + c * 8);
    }
    __syncthreads();

    f32x4 zero = {0.f, 0.f, 0.f, 0.f};
    f32x4 acc[2][4];
    #pragma unroll
    for (int i = 0; i < 2; ++i)
        #pragma unroll
        for (int j = 0; j < 4; ++j) acc[i][j] = zero;

    #pragma unroll
    for (int ks = 0; ks < KT / 32; ++ks) {
        int c_lin = ks * 4 + (l >> 4);
        bf16x8 a[2], bfr[4];
        #pragma unroll
        for (int i = 0; i < 2; ++i) {
            int m = rw + i * 16 + (l & 15);
            int p = (c_lin & ~15) | ((c_lin ^ m) & 15);
            a[i] = *(const bf16x8*)(As + m * KT + p * 8);
        }
        #pragma unroll
        for (int j = 0; j < 4; ++j) {
            int n = cw + j * 16 + (l & 15);
            int p = (c_lin & ~15) | ((c_lin ^ n) & 15);
            bfr[j] = *(const bf16x8*)(Bs + n * KT + p * 8);
        }
        #pragma unroll
        for (int i = 0; i < 2; ++i)
            #pragma unroll
            for (int j = 0; j < 4; ++j)
                acc[i][j] = __builtin_amdgcn_mfma_f32_16x16x32_bf16(a[i], bfr[j], acc[i][j], 0, 0, 0);
    }

    #pragma unroll
    for (int i = 0; i < 2; ++i) {
        int rowbase = bm + rw + i * 16 + (l >> 4) * 4;
        #pragma unroll
        for (int j = 0; j < 4; ++j) {
            int col = bn + cw + j * 16 + (l & 15);
            float v[4];
            #pragma unroll
            for (int reg = 0; reg < 4; ++reg) v[reg] = acc[i][j][reg] + biasz[col];
            if (epi == 2) {
                #pragma unroll
                for (int reg = 0; reg < 4; ++reg)
                    ((float*)Cv)[(size_t)(rowbase + reg) * N + col] =
                        v[reg] + res[(size_t)(rowbase + reg) * N + col];
            } else if (epi == 6) {
                #pragma unroll
                for (int reg = 0; reg < 4; ++reg)
                    ((unsigned short*)Cv)[(size_t)(rowbase + reg) * N + col] = f2b(gelu_exact(v[reg]));
            } else if (epi == 8) {
                int bb = rowbase >> 12, s = rowbase & 4095;
                float4 o;
                o.x = gelu_exact(v[0]) + res[(size_t)(rowbase + 0) * N + col];
                o.y = gelu_exact(v[1]) + res[(size_t)(rowbase + 1) * N + col];
                o.z = gelu_exact(v[2]) + res[(size_t)(rowbase + 2) * N + col];
                o.w = gelu_exact(v[3]) + res[(size_t)(rowbase + 3) * N + col];
                *(float4*)(((float*)Cv) + ((size_t)(bb * 128 + col)) * 4096 + s) = o;
            } else { // epi == 7
                if (z < 2) {
                    unsigned short* dst = ((unsigned short*)Cv) + (size_t)z * MTOT * 128;
                    #pragma unroll
                    for (int reg = 0; reg < 4; ++reg)
                        dst[(size_t)(rowbase + reg) * 128 + col] = f2b(v[reg]);
                } else {
                    int bb = rowbase >> 12, s = rowbase & 4095;
                    ushort4 o;
                    o.x = f2b(v[0]); o.y = f2b(v[1]); o.z = f2b(v[2]); o.w = f2b(v[3]);
                    *(ushort4*)(((unsigned short*)Cv) + (size_t)2 * MTOT * 128 +
                                ((size_t)(bb * 128 + col)) * 4096 + s) = o;
                }
            }
        }
    }
}

// ---------------- Scores via MFMA, bf16 Sc out + fused column-max atomics (batched) ----------------
__global__ __launch_bounds__(256) void scores_mfma(
    const unsigned short* __restrict__ qh, const unsigned short* __restrict__ kh,
    unsigned short* __restrict__ Sc_all, unsigned* __restrict__ gmax_all)
{
    __shared__ unsigned short Qs[128 * 128];
    __shared__ unsigned short Ks[128 * 128];
    __shared__ float cmax[2][128];
    const int b = blockIdx.z;
    const unsigned short* Q = qh + (size_t)b * S * 128;
    const unsigned short* Km = kh + (size_t)b * S * 128;
    unsigned short* Sc = Sc_all + (size_t)b * S * S;
    unsigned* gmax = gmax_all + (size_t)b * S;
    const int bm = blockIdx.y * 128;
    const int bn = blockIdx.x * 128;
    const int tid = threadIdx.x;
    const int w = tid >> 6, l = tid & 63;
    const int wr = (w >> 1) * 64, wc = (w & 1) * 64;

    #pragma unroll
    for (int i = 0; i < 8; ++i) {
        int cid = i * 256 + tid;
        int r = cid >> 4, c = cid & 15;
        int p = c ^ (r & 15);
        *(ulonglong2*)(Qs + r * 128 + p * 8) =
            *(const ulonglong2*)(Q + (size_t)(bm + r) * 128 + c * 8);
        *(ulonglong2*)(Ks + r * 128 + p * 8) =
            *(const ulonglong2*)(Km + (size_t)(bn + r) * 128 + c * 8);
    }
    __syncthreads();

    f32x4 zero = {0.f, 0.f, 0.f, 0.f};
    f32x4 acc[4][4];
    #pragma unroll
    for (int i = 0; i < 4; ++i)
        #pragma unroll
        for (int j = 0; j < 4; ++j) acc[i][j] = zero;

    #pragma unroll
    for (int ks = 0; ks < 4; ++ks) {
        bf16x8 a[4], bfr[4];
        #pragma unroll
        for (int i = 0; i < 4; ++i) {
            int m = wr + i * 16 + (l & 15);
            int p = (ks * 4 + (l >> 4)) ^ (m & 15);
            a[i] = *(const bf16x8*)(Qs + m * 128 + p * 8);
        }
        #pragma unroll
        for (int j = 0; j < 4; ++j) {
            int n = wc + j * 16 + (l & 15);
            int p = (ks * 4 + (l >> 4)) ^ (n & 15);
            bfr[j] = *(const bf16x8*)(Ks + n * 128 + p * 8);
        }
        #pragma unroll
        for (int i = 0; i < 4; ++i)
            #pragma unroll
            for (int j = 0; j < 4; ++j)
                acc[i][j] = __builtin_amdgcn_mfma_f32_16x16x32_bf16(a[i], bfr[j], acc[i][j], 0, 0, 0);
    }

    float jmax[4];
    #pragma unroll
    for (int j = 0; j < 4; ++j) jmax[j] = -INFINITY;
    #pragma unroll
    for (int i = 0; i < 4; ++i) {
        #pragma unroll
        for (int j = 0; j < 4; ++j) {
            int col = bn + wc + j * 16 + (l & 15);
            #pragma unroll
            for (int reg = 0; reg < 4; ++reg) {
                int row = bm + wr + i * 16 + (l >> 4) * 4 + reg;
                float sv = acc[i][j][reg] * SCALE;
                Sc[(size_t)row * S + col] = f2b(sv);
                jmax[j] = fmaxf(jmax[j], sv);
            }
        }
    }
    #pragma unroll
    for (int j = 0; j < 4; ++j) {
        jmax[j] = fmaxf(jmax[j], __shfl_xor(jmax[j], 16));
        jmax[j] = fmaxf(jmax[j], __shfl_xor(jmax[j], 32));
    }
    if (l < 16) {
        #pragma unroll
        for (int j = 0; j < 4; ++j)
            cmax[w >> 1][wc + j * 16 + l] = jmax[j];
    }
    __syncthreads();
    if (tid < 128) {
        float m = fmaxf(cmax[0][tid], cmax[1][tid]);
        atomicMax(gmax + bn + tid, fenc(m));
    }
}

// ---------------- Column sum of exp with known max (batched, bf16 Sc) ----------------
__global__ __launch_bounds__(256) void colsum(
    const unsigned short* __restrict__ Sc_all, const unsigned* __restrict__ gmax_all,
    float* __restrict__ pl)
{
    const int b = blockIdx.z;
    const unsigned short* Sc = Sc_all + (size_t)b * S * S;
    int col = blockIdx.x * 256 + threadIdx.x;
    int r0 = blockIdx.y * 64;
    float M = fdec(gmax_all[(size_t)b * S + col]);
    float acc[8] = {};
    #pragma unroll
    for (int r = 0; r < 64; ++r)
        acc[r & 7] += __expf(b2f(Sc[(size_t)(r0 + r) * S + col]) - M);
    float s = ((acc[0] + acc[1]) + (acc[2] + acc[3])) + ((acc[4] + acc[5]) + (acc[6] + acc[7]));
    pl[((size_t)(b * 64 + blockIdx.y)) * S + col] = s;
}

__global__ __launch_bounds__(256) void colfin(
    const unsigned* __restrict__ gmax_all, const float* __restrict__ pl,
    float* __restrict__ mcol_all, float* __restrict__ rl_all)
{
    const int b = blockIdx.y;
    int col = blockIdx.x * 256 + threadIdx.x;
    float L = 0.f;
    for (int i = 0; i < 64; ++i) L += pl[((size_t)(b * 64 + i)) * S + col];
    mcol_all[(size_t)b * S + col] = fdec(gmax_all[(size_t)b * S + col]);
    rl_all[(size_t)b * S + col] = 1.0f / L;
}

// ---------------- attn@V via MFMA (batched, split-K=2, 8 chunks/block, atomics) ----------------
#define KCH 256
__global__ __launch_bounds__(256) void attnv_mfma(
    const unsigned short* __restrict__ Sc_all, const float* __restrict__ mcol_all,
    const float* __restrict__ rl_all, const unsigned short* __restrict__ Vt_all,
    float* __restrict__ O_all)
{
    __shared__ unsigned short Vs[128 * KCH];  // 64KB
    __shared__ unsigned short Ps[128 * 32];   // 8KB
    const int b = blockIdx.z;
    const unsigned short* Sc = Sc_all + (size_t)b * S * S;
    const float* mcol = mcol_all + (size_t)b * S;
    const float* rl = rl_all + (size_t)b * S;
    const unsigned short* Vt = Vt_all + (size_t)b * 128 * S;
    float* O = O_all + (size_t)b * S * 128;
    const int bq = blockIdx.y * 128;
    const int tid = threadIdx.x;
    const int w = tid >> 6, l = tid & 63;
    const int wr = (w >> 1) * 64, wc = (w & 1) * 64;

    f32x4 zero = {0.f, 0.f, 0.f, 0.f};
    f32x4 acc[4][4];
    #pragma unroll
    for (int i = 0; i < 4; ++i)
        #pragma unroll
        for (int j = 0; j < 4; ++j) acc[i][j] = zero;

    for (int cc = 0; cc < 8; ++cc) {
        int kbase = blockIdx.x * 2048 + cc * KCH;
        __syncthreads();   // prior chunk's MFMA reads of Vs/Ps done
        #pragma unroll
        for (int i = 0; i < 16; ++i) {
            int cid = i * 256 + tid;
            int r = cid >> 5, c = cid & 31;
            int p = c ^ (r & 15);
            *(ulonglong2*)(Vs + r * KCH + p * 8) =
                *(const ulonglong2*)(Vt + (size_t)r * S + kbase + c * 8);
        }
        for (int ks = 0; ks < KCH / 32; ++ks) {
            __syncthreads();
            #pragma unroll
            for (int i = 0; i < 16; ++i) {
                int eid = i * 256 + tid;
                int r = eid >> 5, c = eid & 31;
                int kk = kbase + ks * 32 + c;
                float s = b2f(Sc[(size_t)(bq + r) * S + kk]);
                float pval = __expf(s - mcol[kk]) * rl[kk];
                int pch = (c >> 3) ^ ((r >> 1) & 3);
                Ps[r * 32 + pch * 8 + (c & 7)] = f2b(pval);
            }
            __syncthreads();

            bf16x8 a[4], bfr[4];
            #pragma unroll
            for (int i = 0; i < 4; ++i) {
                int m = wr + i * 16 + (l & 15);
                int pch = (l >> 4) ^ ((m >> 1) & 3);
                a[i] = *(const bf16x8*)(Ps + m * 32 + pch * 8);
            }
            #pragma unroll
            for (int j = 0; j < 4; ++j) {
                int n = wc + j * 16 + (l & 15);
                int p = (ks * 4 + (l >> 4)) ^ (n & 15);
                bfr[j] = *(const bf16x8*)(Vs + n * KCH + p * 8);
            }
            #pragma unroll
            for (int i = 0; i < 4; ++i)
                #pragma unroll
                for (int j = 0; j < 4; ++j)
                    acc[i][j] = __builtin_amdgcn_mfma_f32_16x16x32_bf16(a[i], bfr[j], acc[i][j], 0, 0, 0);
        }
    }

    #pragma unroll
    for (int i = 0; i < 4; ++i) {
        #pragma unroll
        for (int j = 0; j < 4; ++j) {
            int col = wc + j * 16 + (l & 15);
            #pragma unroll
            for (int reg = 0; reg < 4; ++reg) {
                int row = bq + wr + i * 16 + (l >> 4) * 4 + reg;
                atomicAdd(&O[(size_t)row * 128 + col], acc[i][j][reg]);
            }
        }
    }
}

// ---------------- attout fp32 -> bf16 ----------------
__global__ __launch_bounds__(256) void cvt_bf16_4(
    const float4* __restrict__ src, ushort4* __restrict__ dst)
{
    int i = blockIdx.x * 256 + threadIdx.x;
    float4 v = src[i];
    ushort4 o;
    o.x = f2b(v.x); o.y = f2b(v.y); o.z = f2b(v.z); o.w = f2b(v.w);
    dst[i] = o;
}

// ---------------- LayerNorm rows -> bf16 ----------------
__global__ __launch_bounds__(256) void ln_rows(
    const float* __restrict__ y, const float* __restrict__ w, const float* __restrict__ bb,
    unsigned short* __restrict__ zh)
{
    int row = blockIdx.x * 4 + (threadIdx.x >> 6);
    int lane = threadIdx.x & 63;
    const float* yr = y + (size_t)row * CNUM;
    float v0 = yr[lane], v1 = yr[lane + 64];
    float sum = v0 + v1, sq = v0 * v0 + v1 * v1;
    #pragma unroll
    for (int off = 32; off; off >>= 1) {
        sum += __shfl_xor(sum, off);
        sq  += __shfl_xor(sq, off);
    }
    float mean = sum * (1.f / 128.f);
    float var = sq * (1.f / 128.f) - mean * mean;
    float r = rsqrtf(var + EPSLN);
    zh[(size_t)row * CNUM + lane]      = f2b((v0 - mean) * r * w[lane] + bb[lane]);
    zh[(size_t)row * CNUM + lane + 64] = f2b((v1 - mean) * r * w[lane + 64] + bb[lane + 64]);
}

extern "C" void kernel_launch(void* const* d_in, const int* in_sizes, int n_in,
                              void* d_out, int out_size, void* d_ws, size_t ws_size,
                              hipStream_t stream)
{
    (void)in_sizes; (void)n_in; (void)out_size; (void)ws_size;
    const float* x    = (const float*)d_in[0];
    const float* ln1w = (const float*)d_in[1];
    const float* ln1b = (const float*)d_in[2];
    const float* wq   = (const float*)d_in[3];
    const float* bq   = (const float*)d_in[4];
    const float* wk   = (const float*)d_in[5];
    const float* bk   = (const float*)d_in[6];
    const float* wv   = (const float*)d_in[7];
    const float* bv   = (const float*)d_in[8];
    const float* wo   = (const float*)d_in[9];
    const float* bo   = (const float*)d_in[10];
    const float* ln2w = (const float*)d_in[11];
    const float* ln2b = (const float*)d_in[12];
    const float* w1   = (const float*)d_in[13];
    const float* b1   = (const float*)d_in[14];
    const float* w2   = (const float*)d_in[15];
    const float* b2   = (const float*)d_in[16];
    float* out = (float*)d_out;

    float* ws = (float*)d_ws;
    const size_t NSC = (size_t)MTOT * CNUM;            // 2,097,152
    float* t      = ws;
    float* attout = t + NSC;
    float* y      = attout + NSC;
    float* pl     = y + NSC;                           // [4][64][S]
    unsigned* gmax = (unsigned*)(pl + (size_t)BATCH * 64 * S);
    float* mcol   = (float*)(gmax + (size_t)BATCH * S);
    float* rlc    = mcol + (size_t)BATCH * S;
    unsigned short* Sc  = (unsigned short*)(rlc + (size_t)BATCH * S);  // [4][S][S] bf16, 128MB
    unsigned short* xlh = Sc + (size_t)BATCH * S * S;
    unsigned short* qh  = xlh + NSC;
    unsigned short* kh  = qh + NSC;                    // Vt must follow kh (epi 7 contiguity)
    unsigned short* Vt  = kh + NSC;
    unsigned short* attouth = Vt + NSC;
    unsigned short* zh  = attouth + NSC;
    unsigned short* hh  = zh + NSC;                    // [M,256] bf16
    unsigned short* wqkvh = hh + (size_t)MTOT * 256;
    unsigned short* woh = wqkvh + 3 * 16384;
    unsigned short* w1h = woh + 16384;                 // [256][128]
    unsigned short* w2h = w1h + 32768;                 // [128][256]
    float* bqkv = (float*)(w2h + 32768);               // [384]

    ln1_transpose<<<dim3(S / 64, BATCH), 256, 0, stream>>>(x, ln1w, ln1b, xlh, t);
    convw<<<dim3(128, 7), 256, 0, stream>>>(wq, wk, wv, wo, w1, w2, bq, bk, bv,
                                            wqkvh, woh, w1h, w2h, bqkv);

    // QKV: one launch, z = {q, k, v(transposed)}
    gemm_mfma<128><<<dim3(1, MTOT / 64, 3), 256, 0, stream>>>(
        xlh, wqkvh, bqkv, nullptr, qh, 128, 7);

    hipMemsetAsync(attout, 0, NSC * sizeof(float), stream);
    hipMemsetAsync(gmax, 0, (size_t)BATCH * S * sizeof(unsigned), stream);

    scores_mfma<<<dim3(S / 128, S / 128, BATCH), 256, 0, stream>>>(qh, kh, Sc, gmax);
    colsum<<<dim3(S / 256, 64, BATCH), 256, 0, stream>>>(Sc, gmax, pl);
    colfin<<<dim3(S / 256, BATCH), 256, 0, stream>>>(gmax, pl, mcol, rlc);
    attnv_mfma<<<dim3(2, S / 128, BATCH), 256, 0, stream>>>(Sc, mcol, rlc, Vt, attout);

    cvt_bf16_4<<<NSC / 4 / 256, 256, 0, stream>>>((const float4*)attout, (ushort4*)attouth);

    // y = attouth @ wo + bo + t
    gemm_mfma<128><<<dim3(1, MTOT / 64), 256, 0, stream>>>(attouth, woh, bo, t, y, 128, 2);
    ln_rows<<<MTOT / 4, 256, 0, stream>>>(y, ln2w, ln2b, zh);
    // hh = gelu(zh @ w1 + b1) -> bf16
    gemm_mfma<128><<<dim3(2, MTOT / 64), 256, 0, stream>>>(zh, w1h, b1, nullptr, hh, 256, 6);
    // out[b][c][s] = gelu(hh @ w2 + b2) + y   (fused transpose)
    gemm_mfma<256><<<dim3(1, MTOT / 64), 256, 0, stream>>>(hh, w2h, b2, y, out, 128, 8);
}